// Round 5
// baseline (432.701 us; speedup 1.0000x reference)
//
#include <hip/hip_runtime.h>
#include <cstdint>
#include <cstddef>

#define D_NUM 4
#define N_ES  2
#define N_SH  4
#define DIN   512
#define HDIM  256
#define BB    16384
#define MHALF 8192
#define NMAT  12
#define NGATE 36

typedef __bf16 bf16x8 __attribute__((ext_vector_type(8)));
typedef float  f32x4  __attribute__((ext_vector_type(4)));

__device__ __forceinline__ unsigned short f2bf(float f) {
    union { float f; unsigned u; } v; v.f = f;
    unsigned u = v.u;
    unsigned r = (u + 0x7FFFu + ((u >> 16) & 1u)) >> 16;   // RNE
    return (unsigned short)r;
}
__device__ __forceinline__ float bf2f(unsigned short u) {
    union { unsigned u; float f; } v; v.u = ((unsigned)u) << 16; return v.f;
}
__device__ __forceinline__ void async16(void* l, const void* g) {
    __builtin_amdgcn_global_load_lds(
        (const __attribute__((address_space(1))) void*)g,
        (__attribute__((address_space(3))) void*)l,
        16, 0, 0);
}

// ---------------------------------------------------------------------------
// k_wconv: W -> bf16 WT[mat][h][k] via LDS transpose tiles (coalesced).
// ---------------------------------------------------------------------------
__global__ __launch_bounds__(256) void k_wconv(
    const float* __restrict__ Wspec,   // (8,512,256) flattened (mat,k,h)
    const float* __restrict__ Wsh,     // (4,512,256)
    unsigned short* __restrict__ WT)   // (12,256,512)
{
    __shared__ unsigned short t[64][65];
    const int mat = blockIdx.z;
    const int k0  = blockIdx.x * 64;
    const int h0  = blockIdx.y * 64;
    const float* src = (mat < 8) ? (Wspec + (size_t)mat * DIN * HDIM)
                                 : (Wsh   + (size_t)(mat - 8) * DIN * HDIM);
    #pragma unroll
    for (int i = 0; i < 16; ++i) {
        int idx = i * 256 + threadIdx.x;
        int r = idx >> 6, c = idx & 63;
        t[r][c] = f2bf(src[(size_t)(k0 + r) * HDIM + h0 + c]);
    }
    __syncthreads();
    #pragma unroll
    for (int i = 0; i < 16; ++i) {
        int idx = i * 256 + threadIdx.x;
        int r = idx >> 6, c = idx & 63;
        WT[(size_t)mat * HDIM * DIN + (size_t)(h0 + r) * DIN + k0 + c] = t[c][r];
    }
}

// ---------------------------------------------------------------------------
// k_gwt: transpose gate weights. WgT[n][e][k] = Wg[n][k][e]; WgsT[e][k].
// ---------------------------------------------------------------------------
__global__ __launch_bounds__(256) void k_gwt(
    const float* __restrict__ Wg,      // (4,512,6)
    const float* __restrict__ Wgs,     // (512,12)
    float* __restrict__ WgT,           // (4,6,512)
    float* __restrict__ WgsT)          // (12,512)
{
    int i = blockIdx.x * 256 + threadIdx.x;
    if (i < 4 * 6 * 512) {
        int n = i / 3072, rem = i % 3072;
        int e = rem >> 9, k = rem & 511;
        WgT[i] = Wg[((size_t)n * DIN + k) * 6 + e];
    }
    if (i < 12 * 512) {
        int e = i >> 9, k = i & 511;
        WgsT[i] = Wgs[(size_t)k * 12 + e];
    }
}

// ---------------------------------------------------------------------------
// k_prep: x f32 -> bf16 + gates. One wave per TWO rows; all 20 x-loads
// issued up front (MLP). Cross-lane reduction via LDS TRANSPOSE-REDUCE
// (~104 LDS ops/wave) instead of the 432-ds_bpermute butterfly that was
// ~33 us of serialized LDS-pipe time chip-wide.
// ---------------------------------------------------------------------------
__global__ __launch_bounds__(128) void k_prep(
    const float* __restrict__ x,        // (5,B,512)
    const int*   __restrict__ simdom,   // (4,2)
    const float* __restrict__ WgT,      // (4,6,512)
    const float* __restrict__ bg,       // (4,6)
    const float* __restrict__ WgsT,     // (12,512)
    const float* __restrict__ bgs,      // (12)
    unsigned short* __restrict__ xbf,   // (5,B,512)
    float* __restrict__ gates)          // (B,36)
{
    // red[wave][j][lane]: partial j of each lane; stride 68 (writes 2/bank,
    // reads ~5-way on b128 — cheap). 16B-aligned rows (68*4=272, 272%16==0).
    __shared__ __align__(16) float red[2][36][68];
    __shared__ float lgate[2][2][36];   // raw logits per wave-row
    __shared__ float gsm[2][72];        // final gates per wave (2 rows)
    const int wave = threadIdx.x >> 6;
    const int lane = threadIdx.x & 63;
    const int row0 = blockIdx.x * 4 + wave * 2;   // this wave: row0, row0+1
    const int k0   = lane * 8;

    // ---- issue ALL x loads up front: 2 rows x 5 planes x 2 float4 = 20 loads
    float4 a0[5], b0[5], a1[5], b1[5];
    #pragma unroll
    for (int m = 0; m < 5; ++m) {
        const float* xp0 = x + ((size_t)m * BB + row0) * DIN + k0;
        a0[m] = ((const float4*)xp0)[0];
        b0[m] = ((const float4*)xp0)[1];
        const float* xp1 = xp0 + DIN;
        a1[m] = ((const float4*)xp1)[0];
        b1[m] = ((const float4*)xp1)[1];
    }
    __builtin_amdgcn_sched_barrier(0);   // keep loads above, compute below

    float p0[36], p1[36];
    #pragma unroll
    for (int m = 0; m < 5; ++m) {
        // ---- bf16 convert + store (both rows), fire-and-forget
        unsigned short* xbp = xbf + ((size_t)m * BB + row0) * DIN + k0;
        {
            union { unsigned short us[8]; uint4 v; } q0, q1;
            q0.us[0]=f2bf(a0[m].x); q0.us[1]=f2bf(a0[m].y);
            q0.us[2]=f2bf(a0[m].z); q0.us[3]=f2bf(a0[m].w);
            q0.us[4]=f2bf(b0[m].x); q0.us[5]=f2bf(b0[m].y);
            q0.us[6]=f2bf(b0[m].z); q0.us[7]=f2bf(b0[m].w);
            q1.us[0]=f2bf(a1[m].x); q1.us[1]=f2bf(a1[m].y);
            q1.us[2]=f2bf(a1[m].z); q1.us[3]=f2bf(a1[m].w);
            q1.us[4]=f2bf(b1[m].x); q1.us[5]=f2bf(b1[m].y);
            q1.us[6]=f2bf(b1[m].z); q1.us[7]=f2bf(b1[m].w);
            *(uint4*)xbp         = q0.v;
            *(uint4*)(xbp + DIN) = q1.v;
        }
        // ---- per-lane partial dots into p0/p1 (no cross-lane ops here)
        if (m < 4) {
            #pragma unroll
            for (int e = 0; e < 6; ++e) {
                const float* wp = WgT + ((size_t)(m * 6 + e)) * DIN + k0;
                float4 wa = ((const float4*)wp)[0], wb = ((const float4*)wp)[1];
                p0[m*6+e] = a0[m].x*wa.x + a0[m].y*wa.y + a0[m].z*wa.z + a0[m].w*wa.w
                          + b0[m].x*wb.x + b0[m].y*wb.y + b0[m].z*wb.z + b0[m].w*wb.w;
                p1[m*6+e] = a1[m].x*wa.x + a1[m].y*wa.y + a1[m].z*wa.z + a1[m].w*wa.w
                          + b1[m].x*wb.x + b1[m].y*wb.y + b1[m].z*wb.z + b1[m].w*wb.w;
            }
        } else {
            #pragma unroll
            for (int e = 0; e < 12; ++e) {
                const float* wp = WgsT + (size_t)e * DIN + k0;
                float4 wa = ((const float4*)wp)[0], wb = ((const float4*)wp)[1];
                p0[24+e] = a0[m].x*wa.x + a0[m].y*wa.y + a0[m].z*wa.z + a0[m].w*wa.w
                         + b0[m].x*wb.x + b0[m].y*wb.y + b0[m].z*wb.z + b0[m].w*wb.w;
                p1[24+e] = a1[m].x*wa.x + a1[m].y*wa.y + a1[m].z*wa.z + a1[m].w*wa.w
                         + b1[m].x*wb.x + b1[m].y*wb.y + b1[m].z*wb.z + b1[m].w*wb.w;
            }
        }
    }

    // ---- transpose-reduce, row 0 then row 1 (wave-local; LDS pipe in-order)
    float* rbase = &red[wave][0][0];
    #pragma unroll
    for (int jj = 0; jj < 36; ++jj) rbase[jj * 68 + lane] = p0[jj];
    asm volatile("s_waitcnt lgkmcnt(0)" ::: "memory");
    if (lane < 36) {
        const float4* rp = (const float4*)(rbase + lane * 68);
        float s = 0.f;
        #pragma unroll
        for (int c = 0; c < 16; ++c) { float4 v = rp[c]; s += v.x + v.y + v.z + v.w; }
        lgate[wave][0][lane] = s;
    }
    asm volatile("s_waitcnt lgkmcnt(0)" ::: "memory");
    #pragma unroll
    for (int jj = 0; jj < 36; ++jj) rbase[jj * 68 + lane] = p1[jj];
    asm volatile("s_waitcnt lgkmcnt(0)" ::: "memory");
    if (lane < 36) {
        const float4* rp = (const float4*)(rbase + lane * 68);
        float s = 0.f;
        #pragma unroll
        for (int c = 0; c < 16; ++c) { float4 v = rp[c]; s += v.x + v.y + v.z + v.w; }
        lgate[wave][1][lane] = s;
    }
    asm volatile("s_waitcnt lgkmcnt(0)" ::: "memory");
    __builtin_amdgcn_wave_barrier();

    // ---- softmax tail: lane r (r<2) handles its row; wave-local LDS only
    if (lane < 2) {
        const float* lg = lgate[wave][lane];
        float*       go = &gsm[wave][lane * 36];
        #pragma unroll
        for (int n = 0; n < 4; ++n) {
            float z[6];
            #pragma unroll
            for (int e = 0; e < 6; ++e) z[e] = lg[n * 6 + e] + bg[n * 6 + e];
            float mx = z[0];
            #pragma unroll
            for (int e = 1; e < 6; ++e) mx = fmaxf(mx, z[e]);
            float sum = 0.f;
            #pragma unroll
            for (int e = 0; e < 6; ++e) { z[e] = __expf(z[e] - mx); sum += z[e]; }
            float inv = 1.f / sum;
            #pragma unroll
            for (int e = 0; e < 6; ++e) z[e] *= inv;
            int s0 = simdom[n * 2], s1 = simdom[n * 2 + 1];
            float w[6];
            w[0] = z[0]; w[1] = z[1];
            #pragma unroll
            for (int j = 0; j < 4; ++j)
                w[2 + j] = (s0 == j || s1 == j) ? z[2 + j] : -1e30f;
            float mx2 = w[0];
            #pragma unroll
            for (int e = 1; e < 6; ++e) mx2 = fmaxf(mx2, w[e]);
            float sm = 0.f;
            #pragma unroll
            for (int e = 0; e < 6; ++e) { w[e] = __expf(w[e] - mx2); sm += w[e]; }
            float iv = 1.f / sm;
            #pragma unroll
            for (int e = 0; e < 6; ++e) go[n * 6 + e] = w[e] * iv;
        }
        {
            float z[12];
            #pragma unroll
            for (int e = 0; e < 12; ++e) z[e] = lg[24 + e] + bgs[e];
            float mx = z[0];
            #pragma unroll
            for (int e = 1; e < 12; ++e) mx = fmaxf(mx, z[e]);
            float sum = 0.f;
            #pragma unroll
            for (int e = 0; e < 12; ++e) { z[e] = __expf(z[e] - mx); sum += z[e]; }
            float inv = 1.f / sum;
            #pragma unroll
            for (int e = 0; e < 12; ++e) go[24 + e] = z[e] * inv;
        }
    }
    __builtin_amdgcn_wave_barrier();
    // ---- coalesced gate write: wave's 2 rows are contiguous (72 floats)
    for (int j = lane; j < 72; j += 64)
        gates[(size_t)row0 * NGATE + j] = gsm[wave][j];
}

// ---------------------------------------------------------------------------
// k_gemm: batched 12-mat GEMM, m97 structure. Tile 128x128, BK=64, 4 waves.
// grid = (24, 64): x = mat/h-half, y = row-block -> blocks sharing an A
// panel are consecutive; XCD-chunked remap keeps each row-group's 24 blocks
// on one XCD's L2. Epilogue: LDS-transposed, fully-coalesced uint4 stores.
// ---------------------------------------------------------------------------
__global__ __launch_bounds__(256) void k_gemm(
    const unsigned short* __restrict__ xbf,   // (5,B,512)
    const unsigned short* __restrict__ WT,    // (12,256,512)
    const float* __restrict__ bspec,          // (8,256)
    const float* __restrict__ bsh,            // (4,256)
    unsigned short* __restrict__ S,           // (12,MHALF,256)
    int row_base)
{
    // staging uses [0,16384) shorts; epilogue tile uses [0,17408) = 128x136
    __shared__ unsigned short lbuf[17408];

    const int tid  = threadIdx.x;
    const int wave = tid >> 6;
    const int lane = tid & 63;

    // bijective XCD-chunked remap: each XCD gets 8 complete row-groups
    const int j    = blockIdx.x + 24 * blockIdx.y;   // linear id
    const int xcd  = j & 7;
    const int slot = j >> 3;                          // 0..191
    const int rg   = xcd * 8 + slot / 24;             // row-group 0..63
    const int mh   = slot % 24;                       // mat/h-half 0..23

    const int mat  = mh >> 1;
    const int hh0  = (mh & 1) * 128;
    const int plane = (mat < 8) ? (mat >> 1) : 4;
    const int lrow0 = rg * 128;

    const unsigned short* Abase = xbf + ((size_t)plane * BB + row_base + lrow0) * DIN;
    const unsigned short* Bbase = WT + (size_t)mat * HDIM * DIN + (size_t)hh0 * DIN;

    // staging: waves 0,1 -> A rows 0..127; waves 2,3 -> B rows 0..127
    const unsigned short* gb = (wave < 2) ? Abase : Bbase;
    unsigned goff[8];
    unsigned loff[8];
    {
        int cg = (lane & 7) ^ ((lane >> 3) & 7);     // swizzled source chunk
        #pragma unroll
        for (int i = 0; i < 8; ++i) {
            int slot2 = wave * 8 + i;
            int r = (slot2 & 15) * 8 + (lane >> 3);
            goff[i] = (unsigned)(r * DIN + cg * 8);
            loff[i] = (unsigned)(slot2 * 512);       // shorts, wave-uniform
        }
    }

    f32x4 acc[4][4];
    #pragma unroll
    for (int t = 0; t < 4; ++t)
        #pragma unroll
        for (int u = 0; u < 4; ++u)
            acc[t][u] = (f32x4){0.f, 0.f, 0.f, 0.f};

    const int wm = wave >> 1, wn = wave & 1;
    const int arow = lane & 15, quad = lane >> 4;
    int aofs[4], bofs[4];
    #pragma unroll
    for (int t = 0; t < 4; ++t) {
        int r = wm * 64 + t * 16 + arow;
        aofs[t] = r * 64 + (quad ^ (r & 7)) * 8;
    }
    #pragma unroll
    for (int u = 0; u < 4; ++u) {
        int r = wn * 64 + u * 16 + arow;
        bofs[u] = 8192 + r * 64 + (quad ^ (r & 7)) * 8;
    }

    for (int ks = 0; ks < 8; ++ks) {
        __syncthreads();
        #pragma unroll
        for (int i = 0; i < 8; ++i) {
            async16(lbuf + loff[i], gb + goff[i]);
            goff[i] += 64;                            // next BK window
        }
        __syncthreads();

        #pragma unroll
        for (int s2 = 0; s2 < 2; ++s2) {
            const int sx = s2 * 32;                   // flips phys-chunk bit 2
            bf16x8 af[4], bv[4];
            #pragma unroll
            for (int t = 0; t < 4; ++t) af[t] = *(const bf16x8*)(lbuf + (aofs[t] ^ sx));
            #pragma unroll
            for (int u = 0; u < 4; ++u) bv[u] = *(const bf16x8*)(lbuf + (bofs[u] ^ sx));
            #pragma unroll
            for (int t = 0; t < 4; ++t)
                #pragma unroll
                for (int u = 0; u < 4; ++u)
                    acc[t][u] = __builtin_amdgcn_mfma_f32_16x16x32_bf16(af[t], bv[u], acc[t][u], 0, 0, 0);
        }
    }

    // ---- epilogue: bias + ReLU + bf16 -> LDS tile [128][136] -> coalesced
    __syncthreads();                      // last MFMA ds_reads done, lbuf free
    #pragma unroll
    for (int u = 0; u < 4; ++u) {
        const int hc = wn * 64 + u * 16 + arow;       // 0..127 local h
        const float bias = (mat < 8) ? bspec[mat * HDIM + hh0 + hc]
                                     : bsh[(mat - 8) * HDIM + hh0 + hc];
        #pragma unroll
        for (int t = 0; t < 4; ++t) {
            const int rbase = wm * 64 + t * 16 + quad * 4;
            #pragma unroll
            for (int reg = 0; reg < 4; ++reg) {
                float v = fmaxf(acc[t][u][reg] + bias, 0.f);
                lbuf[(rbase + reg) * 136 + hc] = f2bf(v);
            }
        }
    }
    __syncthreads();
    {
        unsigned short* Sb = S + ((size_t)mat * MHALF + lrow0) * HDIM + hh0;
        #pragma unroll
        for (int i = 0; i < 8; ++i) {
            int idx = i * 256 + tid;
            int row = idx >> 4, c8 = idx & 15;
            *(uint4*)(Sb + (size_t)row * HDIM + c8 * 8) =
                *(const uint4*)(lbuf + row * 136 + c8 * 8);
        }
    }
}

// ---------------------------------------------------------------------------
// k_comb: out[n][row][h] from S + gates. Streaming, vectorized: uint
// (2xbf16) S loads, float2 out stores. 8 rows per block.
// ---------------------------------------------------------------------------
__global__ __launch_bounds__(256) void k_comb(
    const unsigned short* __restrict__ S,     // (12,MHALF,256)
    const float* __restrict__ gates,          // (B,36)
    float* __restrict__ out,                  // (5,B,256)
    int row_base)
{
    const int tid = threadIdx.x;
    const int h0  = (tid & 127) * 2;          // h-pair
    const int r0  = blockIdx.x * 8 + (tid >> 7) * 4;
    #pragma unroll
    for (int rr = 0; rr < 4; ++rr) {
        const int lr = r0 + rr;
        const int grow = row_base + lr;
        const float* g = gates + (size_t)grow * NGATE;
        float sa[NMAT], sb[NMAT];
        #pragma unroll
        for (int mat = 0; mat < NMAT; ++mat) {
            unsigned u = *(const unsigned*)(S + ((size_t)mat * MHALF + lr) * HDIM + h0);
            sa[mat] = bf2f((unsigned short)(u & 0xFFFFu));
            sb[mat] = bf2f((unsigned short)(u >> 16));
        }
        float o4a = 0.f, o4b = 0.f;
        #pragma unroll
        for (int j = 0; j < 8; ++j) { o4a += g[24 + j] * sa[j]; o4b += g[24 + j] * sb[j]; }
        #pragma unroll
        for (int e = 0; e < 4; ++e) { o4a += g[32 + e] * sa[8 + e]; o4b += g[32 + e] * sb[8 + e]; }
        #pragma unroll
        for (int n = 0; n < 4; ++n) {
            float ona = g[n*6+0]*sa[n*2] + g[n*6+1]*sa[n*2+1]
                      + g[n*6+2]*sa[8] + g[n*6+3]*sa[9] + g[n*6+4]*sa[10] + g[n*6+5]*sa[11];
            float onb = g[n*6+0]*sb[n*2] + g[n*6+1]*sb[n*2+1]
                      + g[n*6+2]*sb[8] + g[n*6+3]*sb[9] + g[n*6+4]*sb[10] + g[n*6+5]*sb[11];
            float2 o = {ona, onb};
            *(float2*)(out + ((size_t)n * BB + grow) * HDIM + h0) = o;
        }
        float2 o4 = {o4a, o4b};
        *(float2*)(out + ((size_t)4 * BB + grow) * HDIM + h0) = o4;
    }
}

// ---------------------------------------------------------------------------
extern "C" void kernel_launch(void* const* d_in, const int* in_sizes, int n_in,
                              void* d_out, int out_size, void* d_ws, size_t ws_size,
                              hipStream_t stream) {
    const float* x      = (const float*)d_in[0];
    const int*   simdom = (const int*)  d_in[1];
    const float* Wspec  = (const float*)d_in[2];
    const float* bspec  = (const float*)d_in[3];
    const float* Wsh    = (const float*)d_in[4];
    const float* bsh    = (const float*)d_in[5];
    const float* Wg     = (const float*)d_in[6];
    const float* bg     = (const float*)d_in[7];
    const float* Wgs    = (const float*)d_in[8];
    const float* bgs    = (const float*)d_in[9];
    float* out = (float*)d_out;

    uint8_t* ws = (uint8_t*)d_ws;
    unsigned short* xbf  = (unsigned short*)(ws);                      // 83,886,080
    unsigned short* WT   = (unsigned short*)(ws + 83886080ull);        //  3,145,728
    float*          gts  = (float*)(ws + 87031808ull);                 //  2,359,296
    float*          WgT  = (float*)(ws + 89391104ull);                 //     49,152
    float*          WgsT = (float*)(ws + 89440256ull);                 //     24,576
    unsigned short* S    = (unsigned short*)(ws + 89464832ull);        // 50,331,648 (ends ~139.8 MB)

    k_wconv<<<dim3(8, 4, 12), 256, 0, stream>>>(Wspec, Wsh, WT);
    k_gwt<<<48, 256, 0, stream>>>(Wg, Wgs, WgT, WgsT);
    k_prep<<<BB / 4, 128, 0, stream>>>(x, simdom, WgT, bg, WgsT, bgs, xbf, gts);
    for (int half = 0; half < 2; ++half) {
        int row_base = half * MHALF;
        k_gemm<<<dim3(24, 64), 256, 0, stream>>>(xbf, WT, bspec, bsh, S, row_base);
        k_comb<<<MHALF / 8, 256, 0, stream>>>(S, gts, out, row_base);
    }
}

// Round 6
// 401.828 us; speedup vs baseline: 1.0768x; 1.0768x over previous
//
#include <hip/hip_runtime.h>
#include <cstdint>
#include <cstddef>

#define D_NUM 4
#define N_ES  2
#define N_SH  4
#define DIN   512
#define HDIM  256
#define BB    16384
#define MHALF 8192
#define NMAT  12
#define NGATE 36

typedef __bf16 bf16x8 __attribute__((ext_vector_type(8)));
typedef float  f32x4  __attribute__((ext_vector_type(4)));

__device__ __forceinline__ unsigned short f2bf(float f) {
    union { float f; unsigned u; } v; v.f = f;
    unsigned u = v.u;
    unsigned r = (u + 0x7FFFu + ((u >> 16) & 1u)) >> 16;   // RNE
    return (unsigned short)r;
}
__device__ __forceinline__ float bf2f(unsigned short u) {
    union { unsigned u; float f; } v; v.u = ((unsigned)u) << 16; return v.f;
}
__device__ __forceinline__ void async16(void* l, const void* g) {
    __builtin_amdgcn_global_load_lds(
        (const __attribute__((address_space(1))) void*)g,
        (__attribute__((address_space(3))) void*)l,
        16, 0, 0);
}

// ---------------------------------------------------------------------------
// k_wconv: W -> bf16 WT[mat][h][k] via LDS transpose tiles (coalesced).
// ---------------------------------------------------------------------------
__global__ __launch_bounds__(256) void k_wconv(
    const float* __restrict__ Wspec,   // (8,512,256) flattened (mat,k,h)
    const float* __restrict__ Wsh,     // (4,512,256)
    unsigned short* __restrict__ WT)   // (12,256,512)
{
    __shared__ unsigned short t[64][65];
    const int mat = blockIdx.z;
    const int k0  = blockIdx.x * 64;
    const int h0  = blockIdx.y * 64;
    const float* src = (mat < 8) ? (Wspec + (size_t)mat * DIN * HDIM)
                                 : (Wsh   + (size_t)(mat - 8) * DIN * HDIM);
    #pragma unroll
    for (int i = 0; i < 16; ++i) {
        int idx = i * 256 + threadIdx.x;
        int r = idx >> 6, c = idx & 63;
        t[r][c] = f2bf(src[(size_t)(k0 + r) * HDIM + h0 + c]);
    }
    __syncthreads();
    #pragma unroll
    for (int i = 0; i < 16; ++i) {
        int idx = i * 256 + threadIdx.x;
        int r = idx >> 6, c = idx & 63;
        WT[(size_t)mat * HDIM * DIN + (size_t)(h0 + r) * DIN + k0 + c] = t[c][r];
    }
}

// ---------------------------------------------------------------------------
// k_gwt: transpose gate weights. WgT[n][e][k] = Wg[n][k][e]; WgsT[e][k].
// ---------------------------------------------------------------------------
__global__ __launch_bounds__(256) void k_gwt(
    const float* __restrict__ Wg,      // (4,512,6)
    const float* __restrict__ Wgs,     // (512,12)
    float* __restrict__ WgT,           // (4,6,512)
    float* __restrict__ WgsT)          // (12,512)
{
    int i = blockIdx.x * 256 + threadIdx.x;
    if (i < 4 * 6 * 512) {
        int n = i / 3072, rem = i % 3072;
        int e = rem >> 9, k = rem & 511;
        WgT[i] = Wg[((size_t)n * DIN + k) * 6 + e];
    }
    if (i < 12 * 512) {
        int e = i >> 9, k = i & 511;
        WgsT[i] = Wgs[(size_t)k * 12 + e];
    }
}

// ---------------------------------------------------------------------------
// k_prep: x f32 -> bf16 + gates. One wave per TWO rows; all 20 x-loads
// issued up front (MLP). Cross-lane reduction via INCREMENTAL per-plane LDS
// transpose-reduce: each m-group's 6/12 logits are written to LDS right
// away (transient regs only — avoids round-5's 188-VGPR collapse) and
// summed by 12/24 lanes with ds_read_b128. ~200 LDS ops/wave vs the
// 432-shuffle butterfly. LDS 14.2 KB/block; registers ~round-4 level.
// ---------------------------------------------------------------------------
__global__ __launch_bounds__(128) void k_prep(
    const float* __restrict__ x,        // (5,B,512)
    const int*   __restrict__ simdom,   // (4,2)
    const float* __restrict__ WgT,      // (4,6,512)
    const float* __restrict__ bg,       // (4,6)
    const float* __restrict__ WgsT,     // (12,512)
    const float* __restrict__ bgs,      // (12)
    unsigned short* __restrict__ xbf,   // (5,B,512)
    float* __restrict__ gates)          // (B,36)
{
    // red[wave][row][e][lane(+4 pad)]: writes 2 lanes/bank (free);
    // 68*4=272B row stride keeps every row 16B-aligned for b128 reads.
    __shared__ __align__(16) float red[2][2][12][68];
    __shared__ float lgate[2][2][36];   // raw logits per wave-row
    __shared__ float gsm[2][72];        // final gates per wave (2 rows)
    const int wave = threadIdx.x >> 6;
    const int lane = threadIdx.x & 63;
    const int row0 = blockIdx.x * 4 + wave * 2;   // this wave: row0, row0+1
    const int k0   = lane * 8;

    // ---- issue ALL x loads up front: 2 rows x 5 planes x 2 float4 = 20 loads
    float4 a0[5], b0[5], a1[5], b1[5];
    #pragma unroll
    for (int m = 0; m < 5; ++m) {
        const float* xp0 = x + ((size_t)m * BB + row0) * DIN + k0;
        a0[m] = ((const float4*)xp0)[0];
        b0[m] = ((const float4*)xp0)[1];
        const float* xp1 = xp0 + DIN;
        a1[m] = ((const float4*)xp1)[0];
        b1[m] = ((const float4*)xp1)[1];
    }
    __builtin_amdgcn_sched_barrier(0);   // keep loads above, compute below

    #pragma unroll
    for (int m = 0; m < 5; ++m) {
        // ---- bf16 convert + store (both rows), fire-and-forget
        unsigned short* xbp = xbf + ((size_t)m * BB + row0) * DIN + k0;
        {
            union { unsigned short us[8]; uint4 v; } q0, q1;
            q0.us[0]=f2bf(a0[m].x); q0.us[1]=f2bf(a0[m].y);
            q0.us[2]=f2bf(a0[m].z); q0.us[3]=f2bf(a0[m].w);
            q0.us[4]=f2bf(b0[m].x); q0.us[5]=f2bf(b0[m].y);
            q0.us[6]=f2bf(b0[m].z); q0.us[7]=f2bf(b0[m].w);
            q1.us[0]=f2bf(a1[m].x); q1.us[1]=f2bf(a1[m].y);
            q1.us[2]=f2bf(a1[m].z); q1.us[3]=f2bf(a1[m].w);
            q1.us[4]=f2bf(b1[m].x); q1.us[5]=f2bf(b1[m].y);
            q1.us[6]=f2bf(b1[m].z); q1.us[7]=f2bf(b1[m].w);
            *(uint4*)xbp         = q0.v;
            *(uint4*)(xbp + DIN) = q1.v;
        }
        // ---- per-lane partial dots -> immediate LDS write (transient regs)
        if (m < 4) {
            #pragma unroll
            for (int e = 0; e < 6; ++e) {
                const float* wp = WgT + ((size_t)(m * 6 + e)) * DIN + k0;
                float4 wa = ((const float4*)wp)[0], wb = ((const float4*)wp)[1];
                float z0 = a0[m].x*wa.x + a0[m].y*wa.y + a0[m].z*wa.z + a0[m].w*wa.w
                         + b0[m].x*wb.x + b0[m].y*wb.y + b0[m].z*wb.z + b0[m].w*wb.w;
                float z1 = a1[m].x*wa.x + a1[m].y*wa.y + a1[m].z*wa.z + a1[m].w*wa.w
                         + b1[m].x*wb.x + b1[m].y*wb.y + b1[m].z*wb.z + b1[m].w*wb.w;
                red[wave][0][e][lane] = z0;
                red[wave][1][e][lane] = z1;
            }
            asm volatile("s_waitcnt lgkmcnt(0)" ::: "memory");
            if (lane < 12) {
                int r = lane / 6, e = lane % 6;
                const float4* rp = (const float4*)&red[wave][r][e][0];
                float s = 0.f;
                #pragma unroll
                for (int c = 0; c < 16; ++c) { float4 v = rp[c]; s += v.x + v.y + v.z + v.w; }
                lgate[wave][r][m * 6 + e] = s;
            }
        } else {
            #pragma unroll
            for (int e = 0; e < 12; ++e) {
                const float* wp = WgsT + (size_t)e * DIN + k0;
                float4 wa = ((const float4*)wp)[0], wb = ((const float4*)wp)[1];
                float z0 = a0[m].x*wa.x + a0[m].y*wa.y + a0[m].z*wa.z + a0[m].w*wa.w
                         + b0[m].x*wb.x + b0[m].y*wb.y + b0[m].z*wb.z + b0[m].w*wb.w;
                float z1 = a1[m].x*wa.x + a1[m].y*wa.y + a1[m].z*wa.z + a1[m].w*wa.w
                         + b1[m].x*wb.x + b1[m].y*wb.y + b1[m].z*wb.z + b1[m].w*wb.w;
                red[wave][0][e][lane] = z0;
                red[wave][1][e][lane] = z1;
            }
            asm volatile("s_waitcnt lgkmcnt(0)" ::: "memory");
            if (lane < 24) {
                int r = lane / 12, e = lane % 12;
                const float4* rp = (const float4*)&red[wave][r][e][0];
                float s = 0.f;
                #pragma unroll
                for (int c = 0; c < 16; ++c) { float4 v = rp[c]; s += v.x + v.y + v.z + v.w; }
                lgate[wave][r][24 + e] = s;
            }
        }
    }
    asm volatile("s_waitcnt lgkmcnt(0)" ::: "memory");
    __builtin_amdgcn_wave_barrier();

    // ---- softmax tail: lane r (r<2) handles its row; wave-local LDS only
    if (lane < 2) {
        const float* lg = lgate[wave][lane];
        float*       go = &gsm[wave][lane * 36];
        #pragma unroll
        for (int n = 0; n < 4; ++n) {
            float z[6];
            #pragma unroll
            for (int e = 0; e < 6; ++e) z[e] = lg[n * 6 + e] + bg[n * 6 + e];
            float mx = z[0];
            #pragma unroll
            for (int e = 1; e < 6; ++e) mx = fmaxf(mx, z[e]);
            float sum = 0.f;
            #pragma unroll
            for (int e = 0; e < 6; ++e) { z[e] = __expf(z[e] - mx); sum += z[e]; }
            float inv = 1.f / sum;
            #pragma unroll
            for (int e = 0; e < 6; ++e) z[e] *= inv;
            int s0 = simdom[n * 2], s1 = simdom[n * 2 + 1];
            float w[6];
            w[0] = z[0]; w[1] = z[1];
            #pragma unroll
            for (int j = 0; j < 4; ++j)
                w[2 + j] = (s0 == j || s1 == j) ? z[2 + j] : -1e30f;
            float mx2 = w[0];
            #pragma unroll
            for (int e = 1; e < 6; ++e) mx2 = fmaxf(mx2, w[e]);
            float sm = 0.f;
            #pragma unroll
            for (int e = 0; e < 6; ++e) { w[e] = __expf(w[e] - mx2); sm += w[e]; }
            float iv = 1.f / sm;
            #pragma unroll
            for (int e = 0; e < 6; ++e) go[n * 6 + e] = w[e] * iv;
        }
        {
            float z[12];
            #pragma unroll
            for (int e = 0; e < 12; ++e) z[e] = lg[24 + e] + bgs[e];
            float mx = z[0];
            #pragma unroll
            for (int e = 1; e < 12; ++e) mx = fmaxf(mx, z[e]);
            float sum = 0.f;
            #pragma unroll
            for (int e = 0; e < 12; ++e) { z[e] = __expf(z[e] - mx); sum += z[e]; }
            float inv = 1.f / sum;
            #pragma unroll
            for (int e = 0; e < 12; ++e) go[24 + e] = z[e] * inv;
        }
    }
    __builtin_amdgcn_wave_barrier();
    // ---- coalesced gate write: wave's 2 rows are contiguous (72 floats)
    for (int j = lane; j < 72; j += 64)
        gates[(size_t)row0 * NGATE + j] = gsm[wave][j];
}

// ---------------------------------------------------------------------------
// k_gemm: batched 12-mat GEMM, m97 structure. Tile 128x128, BK=64, 4 waves.
// grid = (24, 64): x = mat/h-half, y = row-block -> blocks sharing an A
// panel are consecutive; XCD-chunked remap keeps each row-group's 24 blocks
// on one XCD's L2. Epilogue: LDS-transposed, fully-coalesced uint4 stores.
// ---------------------------------------------------------------------------
__global__ __launch_bounds__(256) void k_gemm(
    const unsigned short* __restrict__ xbf,   // (5,B,512)
    const unsigned short* __restrict__ WT,    // (12,256,512)
    const float* __restrict__ bspec,          // (8,256)
    const float* __restrict__ bsh,            // (4,256)
    unsigned short* __restrict__ S,           // (12,MHALF,256)
    int row_base)
{
    // staging uses [0,16384) shorts; epilogue tile uses [0,17408) = 128x136
    __shared__ unsigned short lbuf[17408];

    const int tid  = threadIdx.x;
    const int wave = tid >> 6;
    const int lane = tid & 63;

    // bijective XCD-chunked remap: each XCD gets 8 complete row-groups
    const int j    = blockIdx.x + 24 * blockIdx.y;   // linear id
    const int xcd  = j & 7;
    const int slot = j >> 3;                          // 0..191
    const int rg   = xcd * 8 + slot / 24;             // row-group 0..63
    const int mh   = slot % 24;                       // mat/h-half 0..23

    const int mat  = mh >> 1;
    const int hh0  = (mh & 1) * 128;
    const int plane = (mat < 8) ? (mat >> 1) : 4;
    const int lrow0 = rg * 128;

    const unsigned short* Abase = xbf + ((size_t)plane * BB + row_base + lrow0) * DIN;
    const unsigned short* Bbase = WT + (size_t)mat * HDIM * DIN + (size_t)hh0 * DIN;

    // staging: waves 0,1 -> A rows 0..127; waves 2,3 -> B rows 0..127
    const unsigned short* gb = (wave < 2) ? Abase : Bbase;
    unsigned goff[8];
    unsigned loff[8];
    {
        int cg = (lane & 7) ^ ((lane >> 3) & 7);     // swizzled source chunk
        #pragma unroll
        for (int i = 0; i < 8; ++i) {
            int slot2 = wave * 8 + i;
            int r = (slot2 & 15) * 8 + (lane >> 3);
            goff[i] = (unsigned)(r * DIN + cg * 8);
            loff[i] = (unsigned)(slot2 * 512);       // shorts, wave-uniform
        }
    }

    f32x4 acc[4][4];
    #pragma unroll
    for (int t = 0; t < 4; ++t)
        #pragma unroll
        for (int u = 0; u < 4; ++u)
            acc[t][u] = (f32x4){0.f, 0.f, 0.f, 0.f};

    const int wm = wave >> 1, wn = wave & 1;
    const int arow = lane & 15, quad = lane >> 4;
    int aofs[4], bofs[4];
    #pragma unroll
    for (int t = 0; t < 4; ++t) {
        int r = wm * 64 + t * 16 + arow;
        aofs[t] = r * 64 + (quad ^ (r & 7)) * 8;
    }
    #pragma unroll
    for (int u = 0; u < 4; ++u) {
        int r = wn * 64 + u * 16 + arow;
        bofs[u] = 8192 + r * 64 + (quad ^ (r & 7)) * 8;
    }

    for (int ks = 0; ks < 8; ++ks) {
        __syncthreads();
        #pragma unroll
        for (int i = 0; i < 8; ++i) {
            async16(lbuf + loff[i], gb + goff[i]);
            goff[i] += 64;                            // next BK window
        }
        __syncthreads();

        #pragma unroll
        for (int s2 = 0; s2 < 2; ++s2) {
            const int sx = s2 * 32;                   // flips phys-chunk bit 2
            bf16x8 af[4], bv[4];
            #pragma unroll
            for (int t = 0; t < 4; ++t) af[t] = *(const bf16x8*)(lbuf + (aofs[t] ^ sx));
            #pragma unroll
            for (int u = 0; u < 4; ++u) bv[u] = *(const bf16x8*)(lbuf + (bofs[u] ^ sx));
            #pragma unroll
            for (int t = 0; t < 4; ++t)
                #pragma unroll
                for (int u = 0; u < 4; ++u)
                    acc[t][u] = __builtin_amdgcn_mfma_f32_16x16x32_bf16(af[t], bv[u], acc[t][u], 0, 0, 0);
        }
    }

    // ---- epilogue: bias + ReLU + bf16 -> LDS tile [128][136] -> coalesced
    __syncthreads();                      // last MFMA ds_reads done, lbuf free
    #pragma unroll
    for (int u = 0; u < 4; ++u) {
        const int hc = wn * 64 + u * 16 + arow;       // 0..127 local h
        const float bias = (mat < 8) ? bspec[mat * HDIM + hh0 + hc]
                                     : bsh[(mat - 8) * HDIM + hh0 + hc];
        #pragma unroll
        for (int t = 0; t < 4; ++t) {
            const int rbase = wm * 64 + t * 16 + quad * 4;
            #pragma unroll
            for (int reg = 0; reg < 4; ++reg) {
                float v = fmaxf(acc[t][u][reg] + bias, 0.f);
                lbuf[(rbase + reg) * 136 + hc] = f2bf(v);
            }
        }
    }
    __syncthreads();
    {
        unsigned short* Sb = S + ((size_t)mat * MHALF + lrow0) * HDIM + hh0;
        #pragma unroll
        for (int i = 0; i < 8; ++i) {
            int idx = i * 256 + tid;
            int row = idx >> 4, c8 = idx & 15;
            *(uint4*)(Sb + (size_t)row * HDIM + c8 * 8) =
                *(const uint4*)(lbuf + row * 136 + c8 * 8);
        }
    }
}

// ---------------------------------------------------------------------------
// k_comb: out[n][row][h] from S + gates. Full-width streaming: uint2
// (4xbf16) S loads (8B/lane), float4 out stores (16B/lane). 8 rows/block:
// thread = (h-quad sub 0..63, row-group tid>>6).
// ---------------------------------------------------------------------------
__global__ __launch_bounds__(256) void k_comb(
    const unsigned short* __restrict__ S,     // (12,MHALF,256)
    const float* __restrict__ gates,          // (B,36)
    float* __restrict__ out,                  // (5,B,256)
    int row_base)
{
    const int tid = threadIdx.x;
    const int h0  = (tid & 63) * 4;           // h-quad
    const int r0  = blockIdx.x * 8 + (tid >> 6) * 2;
    #pragma unroll
    for (int rr = 0; rr < 2; ++rr) {
        const int lr = r0 + rr;
        const int grow = row_base + lr;
        const float* g = gates + (size_t)grow * NGATE;
        float s[NMAT][4];
        #pragma unroll
        for (int mat = 0; mat < NMAT; ++mat) {
            uint2 u = *(const uint2*)(S + ((size_t)mat * MHALF + lr) * HDIM + h0);
            s[mat][0] = bf2f((unsigned short)(u.x & 0xFFFFu));
            s[mat][1] = bf2f((unsigned short)(u.x >> 16));
            s[mat][2] = bf2f((unsigned short)(u.y & 0xFFFFu));
            s[mat][3] = bf2f((unsigned short)(u.y >> 16));
        }
        float o4[4] = {0.f, 0.f, 0.f, 0.f};
        #pragma unroll
        for (int jj = 0; jj < 8; ++jj)
            #pragma unroll
            for (int c = 0; c < 4; ++c) o4[c] += g[24 + jj] * s[jj][c];
        #pragma unroll
        for (int e = 0; e < 4; ++e)
            #pragma unroll
            for (int c = 0; c < 4; ++c) o4[c] += g[32 + e] * s[8 + e][c];
        #pragma unroll
        for (int n = 0; n < 4; ++n) {
            float4 on;
            on.x = g[n*6+0]*s[n*2][0] + g[n*6+1]*s[n*2+1][0]
                 + g[n*6+2]*s[8][0] + g[n*6+3]*s[9][0] + g[n*6+4]*s[10][0] + g[n*6+5]*s[11][0];
            on.y = g[n*6+0]*s[n*2][1] + g[n*6+1]*s[n*2+1][1]
                 + g[n*6+2]*s[8][1] + g[n*6+3]*s[9][1] + g[n*6+4]*s[10][1] + g[n*6+5]*s[11][1];
            on.z = g[n*6+0]*s[n*2][2] + g[n*6+1]*s[n*2+1][2]
                 + g[n*6+2]*s[8][2] + g[n*6+3]*s[9][2] + g[n*6+4]*s[10][2] + g[n*6+5]*s[11][2];
            on.w = g[n*6+0]*s[n*2][3] + g[n*6+1]*s[n*2+1][3]
                 + g[n*6+2]*s[8][3] + g[n*6+3]*s[9][3] + g[n*6+4]*s[10][3] + g[n*6+5]*s[11][3];
            *(float4*)(out + ((size_t)n * BB + grow) * HDIM + h0) = on;
        }
        float4 o4v = {o4[0], o4[1], o4[2], o4[3]};
        *(float4*)(out + ((size_t)4 * BB + grow) * HDIM + h0) = o4v;
    }
}

// ---------------------------------------------------------------------------
extern "C" void kernel_launch(void* const* d_in, const int* in_sizes, int n_in,
                              void* d_out, int out_size, void* d_ws, size_t ws_size,
                              hipStream_t stream) {
    const float* x      = (const float*)d_in[0];
    const int*   simdom = (const int*)  d_in[1];
    const float* Wspec  = (const float*)d_in[2];
    const float* bspec  = (const float*)d_in[3];
    const float* Wsh    = (const float*)d_in[4];
    const float* bsh    = (const float*)d_in[5];
    const float* Wg     = (const float*)d_in[6];
    const float* bg     = (const float*)d_in[7];
    const float* Wgs    = (const float*)d_in[8];
    const float* bgs    = (const float*)d_in[9];
    float* out = (float*)d_out;

    uint8_t* ws = (uint8_t*)d_ws;
    unsigned short* xbf  = (unsigned short*)(ws);                      // 83,886,080
    unsigned short* WT   = (unsigned short*)(ws + 83886080ull);        //  3,145,728
    float*          gts  = (float*)(ws + 87031808ull);                 //  2,359,296
    float*          WgT  = (float*)(ws + 89391104ull);                 //     49,152
    float*          WgsT = (float*)(ws + 89440256ull);                 //     24,576
    unsigned short* S    = (unsigned short*)(ws + 89464832ull);        // 50,331,648 (ends ~139.8 MB)

    k_wconv<<<dim3(8, 4, 12), 256, 0, stream>>>(Wspec, Wsh, WT);
    k_gwt<<<48, 256, 0, stream>>>(Wg, Wgs, WgT, WgsT);
    k_prep<<<BB / 4, 128, 0, stream>>>(x, simdom, WgT, bg, WgsT, bgs, xbf, gts);
    for (int half = 0; half < 2; ++half) {
        int row_base = half * MHALF;
        k_gemm<<<dim3(24, 64), 256, 0, stream>>>(xbf, WT, bspec, bsh, S, row_base);
        k_comb<<<MHALF / 8, 256, 0, stream>>>(S, gts, out, row_base);
    }
}

// Round 7
// 397.228 us; speedup vs baseline: 1.0893x; 1.0116x over previous
//
#include <hip/hip_runtime.h>
#include <cstdint>
#include <cstddef>

#define D_NUM 4
#define N_ES  2
#define N_SH  4
#define DIN   512
#define HDIM  256
#define BB    16384
#define MHALF 8192
#define NMAT  12
#define NGATE 36

typedef __bf16 bf16x8 __attribute__((ext_vector_type(8)));
typedef float  f32x4  __attribute__((ext_vector_type(4)));

__device__ __forceinline__ unsigned short f2bf(float f) {
    union { float f; unsigned u; } v; v.f = f;
    unsigned u = v.u;
    unsigned r = (u + 0x7FFFu + ((u >> 16) & 1u)) >> 16;   // RNE
    return (unsigned short)r;
}
__device__ __forceinline__ float bf2f(unsigned short u) {
    union { unsigned u; float f; } v; v.u = ((unsigned)u) << 16; return v.f;
}
__device__ __forceinline__ void async16(void* l, const void* g) {
    __builtin_amdgcn_global_load_lds(
        (const __attribute__((address_space(1))) void*)g,
        (__attribute__((address_space(3))) void*)l,
        16, 0, 0);
}

// ---- DPP wave-sum (VALU pipe, no LDS-pipe traffic). Result in lane 63.
template<int CTRL, int RMASK>
__device__ __forceinline__ float dpp_sum_step(float v) {
    union { float f; int i; } a, b;
    a.f = v;
    b.i = __builtin_amdgcn_update_dpp(0, a.i, CTRL, RMASK, 0xF, true);
    return v + b.f;
}
__device__ __forceinline__ float wave_sum63(float v) {
    v = dpp_sum_step<0x111, 0xF>(v);   // row_shr:1
    v = dpp_sum_step<0x112, 0xF>(v);   // row_shr:2
    v = dpp_sum_step<0x114, 0xF>(v);   // row_shr:4
    v = dpp_sum_step<0x118, 0xF>(v);   // row_shr:8  -> lane15 of each row
    v = dpp_sum_step<0x142, 0xA>(v);   // row_bcast:15 -> rows 1,3
    v = dpp_sum_step<0x143, 0xC>(v);   // row_bcast:31 -> rows 2,3
    return v;                          // lane 63 = full 64-lane sum
}

// ---------------------------------------------------------------------------
// k_wconv: W -> bf16 WT[mat][h][k] via LDS transpose tiles (coalesced).
// ---------------------------------------------------------------------------
__global__ __launch_bounds__(256) void k_wconv(
    const float* __restrict__ Wspec,   // (8,512,256) flattened (mat,k,h)
    const float* __restrict__ Wsh,     // (4,512,256)
    unsigned short* __restrict__ WT)   // (12,256,512)
{
    __shared__ unsigned short t[64][65];
    const int mat = blockIdx.z;
    const int k0  = blockIdx.x * 64;
    const int h0  = blockIdx.y * 64;
    const float* src = (mat < 8) ? (Wspec + (size_t)mat * DIN * HDIM)
                                 : (Wsh   + (size_t)(mat - 8) * DIN * HDIM);
    #pragma unroll
    for (int i = 0; i < 16; ++i) {
        int idx = i * 256 + threadIdx.x;
        int r = idx >> 6, c = idx & 63;
        t[r][c] = f2bf(src[(size_t)(k0 + r) * HDIM + h0 + c]);
    }
    __syncthreads();
    #pragma unroll
    for (int i = 0; i < 16; ++i) {
        int idx = i * 256 + threadIdx.x;
        int r = idx >> 6, c = idx & 63;
        WT[(size_t)mat * HDIM * DIN + (size_t)(h0 + r) * DIN + k0 + c] = t[c][r];
    }
}

// ---------------------------------------------------------------------------
// k_gwt: transpose gate weights. WgT[n][e][k] = Wg[n][k][e]; WgsT[e][k].
// ---------------------------------------------------------------------------
__global__ __launch_bounds__(256) void k_gwt(
    const float* __restrict__ Wg,      // (4,512,6)
    const float* __restrict__ Wgs,     // (512,12)
    float* __restrict__ WgT,           // (4,6,512)
    float* __restrict__ WgsT)          // (12,512)
{
    int i = blockIdx.x * 256 + threadIdx.x;
    if (i < 4 * 6 * 512) {
        int n = i / 3072, rem = i % 3072;
        int e = rem >> 9, k = rem & 511;
        WgT[i] = Wg[((size_t)n * DIN + k) * 6 + e];
    }
    if (i < 12 * 512) {
        int e = i >> 9, k = i & 511;
        WgsT[i] = Wgs[(size_t)k * 12 + e];
    }
}

// ---------------------------------------------------------------------------
// k_prep: x f32 -> bf16 + gates. One wave per TWO rows; all 20 x-loads
// issued up front (MLP). Cross-lane reduction via DPP (VALU pipe) instead
// of ds_swizzle butterfly / LDS transpose-reduce — removes ~33 us of
// per-CU LDS-pipe occupancy that capped every previous prep variant.
// ---------------------------------------------------------------------------
__global__ __launch_bounds__(128) void k_prep(
    const float* __restrict__ x,        // (5,B,512)
    const int*   __restrict__ simdom,   // (4,2)
    const float* __restrict__ WgT,      // (4,6,512)
    const float* __restrict__ bg,       // (4,6)
    const float* __restrict__ WgsT,     // (12,512)
    const float* __restrict__ bgs,      // (12)
    unsigned short* __restrict__ xbf,   // (5,B,512)
    float* __restrict__ gates)          // (B,36)
{
    __shared__ float lgate[2][2][36];   // raw logits per wave-row
    __shared__ float gsm[2][72];        // final gates per wave (2 rows)
    const int wave = threadIdx.x >> 6;
    const int lane = threadIdx.x & 63;
    const int row0 = blockIdx.x * 4 + wave * 2;   // this wave: row0, row0+1
    const int k0   = lane * 8;

    // ---- issue ALL x loads up front: 2 rows x 5 planes x 2 float4 = 20 loads
    float4 a0[5], b0[5], a1[5], b1[5];
    #pragma unroll
    for (int m = 0; m < 5; ++m) {
        const float* xp0 = x + ((size_t)m * BB + row0) * DIN + k0;
        a0[m] = ((const float4*)xp0)[0];
        b0[m] = ((const float4*)xp0)[1];
        const float* xp1 = xp0 + DIN;
        a1[m] = ((const float4*)xp1)[0];
        b1[m] = ((const float4*)xp1)[1];
    }
    __builtin_amdgcn_sched_barrier(0);   // keep loads above, compute below

    #pragma unroll
    for (int m = 0; m < 5; ++m) {
        // ---- bf16 convert + store (both rows), fire-and-forget
        unsigned short* xbp = xbf + ((size_t)m * BB + row0) * DIN + k0;
        {
            union { unsigned short us[8]; uint4 v; } q0, q1;
            q0.us[0]=f2bf(a0[m].x); q0.us[1]=f2bf(a0[m].y);
            q0.us[2]=f2bf(a0[m].z); q0.us[3]=f2bf(a0[m].w);
            q0.us[4]=f2bf(b0[m].x); q0.us[5]=f2bf(b0[m].y);
            q0.us[6]=f2bf(b0[m].z); q0.us[7]=f2bf(b0[m].w);
            q1.us[0]=f2bf(a1[m].x); q1.us[1]=f2bf(a1[m].y);
            q1.us[2]=f2bf(a1[m].z); q1.us[3]=f2bf(a1[m].w);
            q1.us[4]=f2bf(b1[m].x); q1.us[5]=f2bf(b1[m].y);
            q1.us[6]=f2bf(b1[m].z); q1.us[7]=f2bf(b1[m].w);
            *(uint4*)xbp         = q0.v;
            *(uint4*)(xbp + DIN) = q1.v;
        }
        // ---- gate logit dots + DPP reduce (weights L1/L2-hot)
        if (m < 4) {
            float z0[6], z1[6];
            #pragma unroll
            for (int e = 0; e < 6; ++e) {
                const float* wp = WgT + ((size_t)(m * 6 + e)) * DIN + k0;
                float4 wa = ((const float4*)wp)[0], wb = ((const float4*)wp)[1];
                z0[e] = a0[m].x*wa.x + a0[m].y*wa.y + a0[m].z*wa.z + a0[m].w*wa.w
                      + b0[m].x*wb.x + b0[m].y*wb.y + b0[m].z*wb.z + b0[m].w*wb.w;
                z1[e] = a1[m].x*wa.x + a1[m].y*wa.y + a1[m].z*wa.z + a1[m].w*wa.w
                      + b1[m].x*wb.x + b1[m].y*wb.y + b1[m].z*wb.z + b1[m].w*wb.w;
            }
            #pragma unroll
            for (int e = 0; e < 6; ++e) { z0[e] = wave_sum63(z0[e]); z1[e] = wave_sum63(z1[e]); }
            if (lane == 63) {
                #pragma unroll
                for (int e = 0; e < 6; ++e) {
                    lgate[wave][0][m * 6 + e] = z0[e];
                    lgate[wave][1][m * 6 + e] = z1[e];
                }
            }
        } else {
            float z0[12], z1[12];
            #pragma unroll
            for (int e = 0; e < 12; ++e) {
                const float* wp = WgsT + (size_t)e * DIN + k0;
                float4 wa = ((const float4*)wp)[0], wb = ((const float4*)wp)[1];
                z0[e] = a0[m].x*wa.x + a0[m].y*wa.y + a0[m].z*wa.z + a0[m].w*wa.w
                      + b0[m].x*wb.x + b0[m].y*wb.y + b0[m].z*wb.z + b0[m].w*wb.w;
                z1[e] = a1[m].x*wa.x + a1[m].y*wa.y + a1[m].z*wa.z + a1[m].w*wa.w
                      + b1[m].x*wb.x + b1[m].y*wb.y + b1[m].z*wb.z + b1[m].w*wb.w;
            }
            #pragma unroll
            for (int e = 0; e < 12; ++e) { z0[e] = wave_sum63(z0[e]); z1[e] = wave_sum63(z1[e]); }
            if (lane == 63) {
                #pragma unroll
                for (int e = 0; e < 12; ++e) {
                    lgate[wave][0][24 + e] = z0[e];
                    lgate[wave][1][24 + e] = z1[e];
                }
            }
        }
    }
    asm volatile("s_waitcnt lgkmcnt(0)" ::: "memory");
    __builtin_amdgcn_wave_barrier();

    // ---- softmax tail: lane r (r<2) handles its row; wave-local LDS only
    if (lane < 2) {
        const float* lg = lgate[wave][lane];
        float*       go = &gsm[wave][lane * 36];
        #pragma unroll
        for (int n = 0; n < 4; ++n) {
            float z[6];
            #pragma unroll
            for (int e = 0; e < 6; ++e) z[e] = lg[n * 6 + e] + bg[n * 6 + e];
            float mx = z[0];
            #pragma unroll
            for (int e = 1; e < 6; ++e) mx = fmaxf(mx, z[e]);
            float sum = 0.f;
            #pragma unroll
            for (int e = 0; e < 6; ++e) { z[e] = __expf(z[e] - mx); sum += z[e]; }
            float inv = 1.f / sum;
            #pragma unroll
            for (int e = 0; e < 6; ++e) z[e] *= inv;
            int s0 = simdom[n * 2], s1 = simdom[n * 2 + 1];
            float w[6];
            w[0] = z[0]; w[1] = z[1];
            #pragma unroll
            for (int j = 0; j < 4; ++j)
                w[2 + j] = (s0 == j || s1 == j) ? z[2 + j] : -1e30f;
            float mx2 = w[0];
            #pragma unroll
            for (int e = 1; e < 6; ++e) mx2 = fmaxf(mx2, w[e]);
            float sm = 0.f;
            #pragma unroll
            for (int e = 0; e < 6; ++e) { w[e] = __expf(w[e] - mx2); sm += w[e]; }
            float iv = 1.f / sm;
            #pragma unroll
            for (int e = 0; e < 6; ++e) go[n * 6 + e] = w[e] * iv;
        }
        {
            float z[12];
            #pragma unroll
            for (int e = 0; e < 12; ++e) z[e] = lg[24 + e] + bgs[e];
            float mx = z[0];
            #pragma unroll
            for (int e = 1; e < 12; ++e) mx = fmaxf(mx, z[e]);
            float sum = 0.f;
            #pragma unroll
            for (int e = 0; e < 12; ++e) { z[e] = __expf(z[e] - mx); sum += z[e]; }
            float inv = 1.f / sum;
            #pragma unroll
            for (int e = 0; e < 12; ++e) go[24 + e] = z[e] * inv;
        }
    }
    __builtin_amdgcn_wave_barrier();
    // ---- coalesced gate write: wave's 2 rows are contiguous (72 floats)
    for (int j = lane; j < 72; j += 64)
        gates[(size_t)row0 * NGATE + j] = gsm[wave][j];
}

// ---------------------------------------------------------------------------
// k_gemm: batched 12-mat GEMM, m97 structure. Tile 128x128, BK=64, 4 waves.
// grid = (24, 64): x = mat/h-half, y = row-block -> blocks sharing an A
// panel are consecutive; XCD-chunked remap keeps each row-group's 24 blocks
// on one XCD's L2. Epilogue: LDS-transposed, fully-coalesced uint4 stores.
// ---------------------------------------------------------------------------
__global__ __launch_bounds__(256) void k_gemm(
    const unsigned short* __restrict__ xbf,   // (5,B,512)
    const unsigned short* __restrict__ WT,    // (12,256,512)
    const float* __restrict__ bspec,          // (8,256)
    const float* __restrict__ bsh,            // (4,256)
    unsigned short* __restrict__ S,           // (12,MHALF,256)
    int row_base)
{
    // staging uses [0,16384) shorts; epilogue tile uses [0,17408) = 128x136
    __shared__ unsigned short lbuf[17408];

    const int tid  = threadIdx.x;
    const int wave = tid >> 6;
    const int lane = tid & 63;

    // bijective XCD-chunked remap: each XCD gets 8 complete row-groups
    const int j    = blockIdx.x + 24 * blockIdx.y;   // linear id
    const int xcd  = j & 7;
    const int slot = j >> 3;                          // 0..191
    const int rg   = xcd * 8 + slot / 24;             // row-group 0..63
    const int mh   = slot % 24;                       // mat/h-half 0..23

    const int mat  = mh >> 1;
    const int hh0  = (mh & 1) * 128;
    const int plane = (mat < 8) ? (mat >> 1) : 4;
    const int lrow0 = rg * 128;

    const unsigned short* Abase = xbf + ((size_t)plane * BB + row_base + lrow0) * DIN;
    const unsigned short* Bbase = WT + (size_t)mat * HDIM * DIN + (size_t)hh0 * DIN;

    // staging: waves 0,1 -> A rows 0..127; waves 2,3 -> B rows 0..127
    const unsigned short* gb = (wave < 2) ? Abase : Bbase;
    unsigned goff[8];
    unsigned loff[8];
    {
        int cg = (lane & 7) ^ ((lane >> 3) & 7);     // swizzled source chunk
        #pragma unroll
        for (int i = 0; i < 8; ++i) {
            int slot2 = wave * 8 + i;
            int r = (slot2 & 15) * 8 + (lane >> 3);
            goff[i] = (unsigned)(r * DIN + cg * 8);
            loff[i] = (unsigned)(slot2 * 512);       // shorts, wave-uniform
        }
    }

    f32x4 acc[4][4];
    #pragma unroll
    for (int t = 0; t < 4; ++t)
        #pragma unroll
        for (int u = 0; u < 4; ++u)
            acc[t][u] = (f32x4){0.f, 0.f, 0.f, 0.f};

    const int wm = wave >> 1, wn = wave & 1;
    const int arow = lane & 15, quad = lane >> 4;
    int aofs[4], bofs[4];
    #pragma unroll
    for (int t = 0; t < 4; ++t) {
        int r = wm * 64 + t * 16 + arow;
        aofs[t] = r * 64 + (quad ^ (r & 7)) * 8;
    }
    #pragma unroll
    for (int u = 0; u < 4; ++u) {
        int r = wn * 64 + u * 16 + arow;
        bofs[u] = 8192 + r * 64 + (quad ^ (r & 7)) * 8;
    }

    for (int ks = 0; ks < 8; ++ks) {
        __syncthreads();
        #pragma unroll
        for (int i = 0; i < 8; ++i) {
            async16(lbuf + loff[i], gb + goff[i]);
            goff[i] += 64;                            // next BK window
        }
        __syncthreads();

        #pragma unroll
        for (int s2 = 0; s2 < 2; ++s2) {
            const int sx = s2 * 32;                   // flips phys-chunk bit 2
            bf16x8 af[4], bv[4];
            #pragma unroll
            for (int t = 0; t < 4; ++t) af[t] = *(const bf16x8*)(lbuf + (aofs[t] ^ sx));
            #pragma unroll
            for (int u = 0; u < 4; ++u) bv[u] = *(const bf16x8*)(lbuf + (bofs[u] ^ sx));
            #pragma unroll
            for (int t = 0; t < 4; ++t)
                #pragma unroll
                for (int u = 0; u < 4; ++u)
                    acc[t][u] = __builtin_amdgcn_mfma_f32_16x16x32_bf16(af[t], bv[u], acc[t][u], 0, 0, 0);
        }
    }

    // ---- epilogue: bias + ReLU + bf16 -> LDS tile [128][136] -> coalesced
    __syncthreads();                      // last MFMA ds_reads done, lbuf free
    #pragma unroll
    for (int u = 0; u < 4; ++u) {
        const int hc = wn * 64 + u * 16 + arow;       // 0..127 local h
        const float bias = (mat < 8) ? bspec[mat * HDIM + hh0 + hc]
                                     : bsh[(mat - 8) * HDIM + hh0 + hc];
        #pragma unroll
        for (int t = 0; t < 4; ++t) {
            const int rbase = wm * 64 + t * 16 + quad * 4;
            #pragma unroll
            for (int reg = 0; reg < 4; ++reg) {
                float v = fmaxf(acc[t][u][reg] + bias, 0.f);
                lbuf[(rbase + reg) * 136 + hc] = f2bf(v);
            }
        }
    }
    __syncthreads();
    {
        unsigned short* Sb = S + ((size_t)mat * MHALF + lrow0) * HDIM + hh0;
        #pragma unroll
        for (int i = 0; i < 8; ++i) {
            int idx = i * 256 + tid;
            int row = idx >> 4, c8 = idx & 15;
            *(uint4*)(Sb + (size_t)row * HDIM + c8 * 8) =
                *(const uint4*)(lbuf + row * 136 + c8 * 8);
        }
    }
}

// ---------------------------------------------------------------------------
// k_comb: out[n][row][h] from S + gates. Full-width streaming: uint2
// (4xbf16) S loads (8B/lane), float4 out stores (16B/lane). 8 rows/block:
// thread = (h-quad sub 0..63, row-group tid>>6).
// ---------------------------------------------------------------------------
__global__ __launch_bounds__(256) void k_comb(
    const unsigned short* __restrict__ S,     // (12,MHALF,256)
    const float* __restrict__ gates,          // (B,36)
    float* __restrict__ out,                  // (5,B,256)
    int row_base)
{
    const int tid = threadIdx.x;
    const int h0  = (tid & 63) * 4;           // h-quad
    const int r0  = blockIdx.x * 8 + (tid >> 6) * 2;
    #pragma unroll
    for (int rr = 0; rr < 2; ++rr) {
        const int lr = r0 + rr;
        const int grow = row_base + lr;
        const float* g = gates + (size_t)grow * NGATE;
        float s[NMAT][4];
        #pragma unroll
        for (int mat = 0; mat < NMAT; ++mat) {
            uint2 u = *(const uint2*)(S + ((size_t)mat * MHALF + lr) * HDIM + h0);
            s[mat][0] = bf2f((unsigned short)(u.x & 0xFFFFu));
            s[mat][1] = bf2f((unsigned short)(u.x >> 16));
            s[mat][2] = bf2f((unsigned short)(u.y & 0xFFFFu));
            s[mat][3] = bf2f((unsigned short)(u.y >> 16));
        }
        float o4[4] = {0.f, 0.f, 0.f, 0.f};
        #pragma unroll
        for (int jj = 0; jj < 8; ++jj)
            #pragma unroll
            for (int c = 0; c < 4; ++c) o4[c] += g[24 + jj] * s[jj][c];
        #pragma unroll
        for (int e = 0; e < 4; ++e)
            #pragma unroll
            for (int c = 0; c < 4; ++c) o4[c] += g[32 + e] * s[8 + e][c];
        #pragma unroll
        for (int n = 0; n < 4; ++n) {
            float4 on;
            on.x = g[n*6+0]*s[n*2][0] + g[n*6+1]*s[n*2+1][0]
                 + g[n*6+2]*s[8][0] + g[n*6+3]*s[9][0] + g[n*6+4]*s[10][0] + g[n*6+5]*s[11][0];
            on.y = g[n*6+0]*s[n*2][1] + g[n*6+1]*s[n*2+1][1]
                 + g[n*6+2]*s[8][1] + g[n*6+3]*s[9][1] + g[n*6+4]*s[10][1] + g[n*6+5]*s[11][1];
            on.z = g[n*6+0]*s[n*2][2] + g[n*6+1]*s[n*2+1][2]
                 + g[n*6+2]*s[8][2] + g[n*6+3]*s[9][2] + g[n*6+4]*s[10][2] + g[n*6+5]*s[11][2];
            on.w = g[n*6+0]*s[n*2][3] + g[n*6+1]*s[n*2+1][3]
                 + g[n*6+2]*s[8][3] + g[n*6+3]*s[9][3] + g[n*6+4]*s[10][3] + g[n*6+5]*s[11][3];
            *(float4*)(out + ((size_t)n * BB + grow) * HDIM + h0) = on;
        }
        float4 o4v = {o4[0], o4[1], o4[2], o4[3]};
        *(float4*)(out + ((size_t)4 * BB + grow) * HDIM + h0) = o4v;
    }
}

// ---------------------------------------------------------------------------
extern "C" void kernel_launch(void* const* d_in, const int* in_sizes, int n_in,
                              void* d_out, int out_size, void* d_ws, size_t ws_size,
                              hipStream_t stream) {
    const float* x      = (const float*)d_in[0];
    const int*   simdom = (const int*)  d_in[1];
    const float* Wspec  = (const float*)d_in[2];
    const float* bspec  = (const float*)d_in[3];
    const float* Wsh    = (const float*)d_in[4];
    const float* bsh    = (const float*)d_in[5];
    const float* Wg     = (const float*)d_in[6];
    const float* bg     = (const float*)d_in[7];
    const float* Wgs    = (const float*)d_in[8];
    const float* bgs    = (const float*)d_in[9];
    float* out = (float*)d_out;

    uint8_t* ws = (uint8_t*)d_ws;
    unsigned short* xbf  = (unsigned short*)(ws);                      // 83,886,080
    unsigned short* WT   = (unsigned short*)(ws + 83886080ull);        //  3,145,728
    float*          gts  = (float*)(ws + 87031808ull);                 //  2,359,296
    float*          WgT  = (float*)(ws + 89391104ull);                 //     49,152
    float*          WgsT = (float*)(ws + 89440256ull);                 //     24,576
    unsigned short* S    = (unsigned short*)(ws + 89464832ull);        // 50,331,648 (ends ~139.8 MB)

    k_wconv<<<dim3(8, 4, 12), 256, 0, stream>>>(Wspec, Wsh, WT);
    k_gwt<<<48, 256, 0, stream>>>(Wg, Wgs, WgT, WgsT);
    k_prep<<<BB / 4, 128, 0, stream>>>(x, simdom, WgT, bg, WgsT, bgs, xbf, gts);
    for (int half = 0; half < 2; ++half) {
        int row_base = half * MHALF;
        k_gemm<<<dim3(24, 64), 256, 0, stream>>>(xbf, WT, bspec, bsh, S, row_base);
        k_comb<<<MHALF / 8, 256, 0, stream>>>(S, gts, out, row_base);
    }
}